// Round 6
// baseline (55.997 us; speedup 1.0000x reference)
//
#include <hip/hip_runtime.h>
#include <hip/hip_bf16.h>
#include <math.h>

// B=16, H=W=256, 150 hidden channels, K=20 value-iteration steps.
//
// pack_a_kernel: partitions channels by sign(Wp), scales each row
//   (9 taps + bias) by SIGNED Wp[ch], packs into MFMA A-fragment layout
//   (6 groups of 32 rows, zero-padded). Header stores nPosG.
//   Then conv's epilogue is sum of max(u,0) over pos groups + min(u,0)
//   over neg groups: Wp*relu(h) == max(Wp*h,0) if Wp>=0, min(Wp*h,0) if Wp<0.
// conv_p_mfma: p = sigmoid(sum). mfma_f32_32x32x16_bf16, K=16 = 9 taps +
//   bias slot. Strip-per-wave, direct per-lane tap loads (no shuffles),
//   A-frags via LDS, one accumulator live at a time (-> ~50 VGPR, 8 waves/SIMD).
// mvprop_kernel: unchanged from R2 (~20.6us by subtraction).

#define SENT -1e30f

typedef short short8 __attribute__((ext_vector_type(8)));
typedef float f32x16 __attribute__((ext_vector_type(16)));

__device__ __forceinline__ uint32_t pkbf(float lo, float hi) {
    uint32_t r;
    asm("v_cvt_pk_bf16_f32 %0, %1, %2" : "=v"(r) : "v"(lo), "v"(hi));
    return r;
}

__device__ __forceinline__ uint32_t bfu(float f) {
    __hip_bfloat16 h = __float2bfloat16(f);
    ushort u; __builtin_memcpy(&u, &h, 2);
    return (uint32_t)u;
}

// ---- setup: sign-partition + scale + pack A fragments. grid=1, block=256.
__global__ void pack_a_kernel(const float* __restrict__ Wh,
                              const float* __restrict__ bh,
                              const float* __restrict__ Wp,
                              uint4* __restrict__ wsA)
{
    __shared__ int scan[256];
    const int tid = threadIdx.x;
    const bool valid = tid < 150;
    float wp = valid ? Wp[tid] : 0.f;
    bool pos = valid && (wp >= 0.f);
    bool neg = valid && (wp < 0.f);

    // inclusive prefix scan of (pos, neg) packed in one int
    int v = (pos ? 1 : 0) | ((neg ? 1 : 0) << 16);
    scan[tid] = v;
    __syncthreads();
    for (int off = 1; off < 256; off <<= 1) {
        int x = scan[tid];
        int y = (tid >= off) ? scan[tid - off] : 0;
        __syncthreads();
        scan[tid] = x + y;
        __syncthreads();
    }
    int incl  = scan[tid];
    int total = scan[255];
    int P     = total & 0xffff;
    int rankPos = (incl & 0xffff) - (pos ? 1 : 0);
    int rankNeg = (incl >> 16)    - (neg ? 1 : 0);
    int Ppad  = (P + 31) & ~31;
    int nPosG = Ppad >> 5;
    int newidx = pos ? rankPos : (Ppad + rankNeg);

    // zero-init the 6*64 fragment slots + write header
    if (tid < 384) wsA[tid] = make_uint4(0u, 0u, 0u, 0u);
    if (tid == 0)  ((uint32_t*)(wsA + 384))[0] = (uint32_t)nPosG;
    __syncthreads();   // drains global writes before the scatter below

    if (valid) {
        float s  = wp;  // signed scale folds Wp into the GEMM
        float w0 = Wh[tid*9+0]*s, w1 = Wh[tid*9+1]*s, w2 = Wh[tid*9+2]*s;
        float w3 = Wh[tid*9+3]*s, w4 = Wh[tid*9+4]*s, w5 = Wh[tid*9+5]*s;
        float w6 = Wh[tid*9+6]*s, w7 = Wh[tid*9+7]*s, w8 = Wh[tid*9+8]*s;
        float bb = bh[tid]*s;
        int g = newidx >> 5, col0 = newidx & 31;
        uint4 q;
        q.x = (bfu(w1) << 16) | bfu(w0);
        q.y = (bfu(w3) << 16) | bfu(w2);
        q.z = (bfu(w5) << 16) | bfu(w4);
        q.w = (bfu(w7) << 16) | bfu(w6);
        wsA[g * 64 + col0] = q;                 // half 0: k=0..7
        q.x = (bfu(bb) << 16) | bfu(w8);        // half 1: k=8 tap, k=9 bias
        q.y = 0; q.z = 0; q.w = 0;
        wsA[g * 64 + 32 + col0] = q;
    }
}

__global__ __launch_bounds__(256, 4) void conv_p_mfma(
    const float* __restrict__ image, const uint4* __restrict__ wsA,
    float* __restrict__ pout)
{
    const int tid  = threadIdx.x;
    const int wv   = tid >> 6;
    const int lane = tid & 63;
    const int half = lane >> 5;
    const int col0 = lane & 31;
    const int b    = blockIdx.z;
    const int y    = blockIdx.y * 4 + wv;     // wave's row (block = 4 consec rows)
    const int px   = blockIdx.x * 32 + col0;  // wave's 32-px strip
    const float* occ = image + (size_t)b * 131072;

    // stage A fragments into LDS (384 x 16B = 6 KB)
    __shared__ __align__(16) uint4 lds_a[384];
    lds_a[tid] = wsA[tid];
    if (tid < 128) lds_a[256 + tid] = wsA[256 + tid];
    uint32_t nPosG = __builtin_amdgcn_readfirstlane(((const uint32_t*)(wsA + 384))[0]);

    // direct per-lane 3x3 taps (both halves load pixel px's taps; L1-served)
    float t0, t1, t2, t3, t4, t5, t6, t7, t8;
    {
        bool x0ok = (px >= 1), x2ok = (px <= 254);
        int xm = px - 1, xp = px + 1;
        bool y0ok = (y >= 1), y2ok = (y <= 254);
        const float* rm = occ + (y - 1) * 256;
        const float* rc = occ + y * 256;
        const float* rp = occ + (y + 1) * 256;
        t0 = (y0ok & x0ok) ? rm[xm] : 0.f;
        t1 =  y0ok         ? rm[px] : 0.f;
        t2 = (y0ok & x2ok) ? rm[xp] : 0.f;
        t3 =  x0ok         ? rc[xm] : 0.f;
        t4 =                 rc[px];
        t5 =  x2ok         ? rc[xp] : 0.f;
        t6 = (y2ok & x0ok) ? rp[xm] : 0.f;
        t7 =  y2ok         ? rp[px] : 0.f;
        t8 = (y2ok & x2ok) ? rp[xp] : 0.f;
    }
    __syncthreads();

    // B fragment: half0 -> k=0..7 = t0..t7; half1 -> k=8 = t8, k=9 = 1.0
    union { uint32_t u[4]; short8 s; } bb;
    bb.u[0] = half ? pkbf(t8, 1.0f) : pkbf(t0, t1);
    bb.u[1] = half ? 0u : pkbf(t2, t3);
    bb.u[2] = half ? 0u : pkbf(t4, t5);
    bb.u[3] = half ? 0u : pkbf(t6, t7);
    short8 bfr = bb.s;

    const f32x16 kZero = {};
    float S0 = 0.f, S1 = 0.f, S2 = 0.f, S3 = 0.f;
#pragma unroll
    for (uint32_t g = 0; g < 6; ++g) {
        union { uint4 q; short8 s; } ua;
        ua.q = lds_a[g * 64 + lane];
        f32x16 d = __builtin_amdgcn_mfma_f32_32x32x16_bf16(ua.s, bfr, kZero, 0, 0, 0);
        if (g < nPosG) {      // wave-uniform branch: positive-Wp groups
#pragma unroll
            for (int q = 0; q < 4; ++q) {
                S0 += fmaxf(d[q*4+0], 0.f);
                S1 += fmaxf(d[q*4+1], 0.f);
                S2 += fmaxf(d[q*4+2], 0.f);
                S3 += fmaxf(d[q*4+3], 0.f);
            }
        } else {              // negative-Wp groups (zero-pad rows add 0)
#pragma unroll
            for (int q = 0; q < 4; ++q) {
                S0 += fminf(d[q*4+0], 0.f);
                S1 += fminf(d[q*4+1], 0.f);
                S2 += fminf(d[q*4+2], 0.f);
                S3 += fminf(d[q*4+3], 0.f);
            }
        }
    }

    float s = (S0 + S1) + (S2 + S3);
    s += __shfl_xor(s, 32);   // combine the two half-wave channel sets

    float p = 1.f / (1.f + __expf(-s));
    if (!half)
        pout[(size_t)b * 65536 + y * 256 + px] = p;
}

__global__ __launch_bounds__(512, 2) void mvprop_kernel(
    const float* __restrict__ image, const float* __restrict__ pbuf,
    float* __restrict__ out)
{
    const int tid  = threadIdx.x;
    const int w    = tid >> 6;          // wave 0..7, owns ext rows 7w..7w+6
    const int lane = tid & 63;          // lane owns cols 4*lane..4*lane+3
    const int b    = blockIdx.z;
    const int gy0  = blockIdx.y * 16 - 20;   // ext row 0 -> global row gy0
    const int x4   = lane * 4;

    const float* rimg = image + (size_t)b * 131072 + 65536;  // channel 1
    const float* pp   = pbuf  + (size_t)b * 65536;

    float v[7][4], r[7][4], p[7][4];
#pragma unroll
    for (int i = 0; i < 7; ++i) {
        int gy = gy0 + w * 7 + i;
        if (gy >= 0 && gy < 256) {
            float4 rv = *(const float4*)&rimg[gy * 256 + x4];
            float4 pv = *(const float4*)&pp[gy * 256 + x4];
            r[i][0] = rv.x; r[i][1] = rv.y; r[i][2] = rv.z; r[i][3] = rv.w;
            p[i][0] = pv.x; p[i][1] = pv.y; p[i][2] = pv.z; p[i][3] = pv.w;
        } else {
            r[i][0] = r[i][1] = r[i][2] = r[i][3] = SENT;
            p[i][0] = p[i][1] = p[i][2] = p[i][3] = 0.f;
        }
        v[i][0] = r[i][0]; v[i][1] = r[i][1];
        v[i][2] = r[i][2]; v[i][3] = r[i][3];
    }

    __shared__ float4 gT[2][8][64];
    __shared__ float4 gB[2][8][64];

    for (int t = 0; t < 20; ++t) {
        int bf = t & 1;
        gT[bf][w][lane] = make_float4(v[0][0], v[0][1], v[0][2], v[0][3]);
        gB[bf][w][lane] = make_float4(v[6][0], v[6][1], v[6][2], v[6][3]);
        __syncthreads();
        float4 abv = (w > 0) ? gB[bf][w - 1][lane]
                             : make_float4(SENT, SENT, SENT, SENT);
        float4 blw = (w < 7) ? gT[bf][w + 1][lane]
                             : make_float4(SENT, SENT, SENT, SENT);

        float pv0 = abv.x, pv1 = abv.y, pv2 = abv.z, pv3 = abv.w;
#pragma unroll
        for (int i = 0; i < 7; ++i) {
            float c0 = v[i][0], c1 = v[i][1], c2 = v[i][2], c3 = v[i][3];
            float n0, n1, n2, n3;
            if (i < 6) { n0 = v[i+1][0]; n1 = v[i+1][1]; n2 = v[i+1][2]; n3 = v[i+1][3]; }
            else       { n0 = blw.x;     n1 = blw.y;     n2 = blw.z;     n3 = blw.w;     }
            float vm0 = fmaxf(pv0, fmaxf(c0, n0));
            float vm1 = fmaxf(pv1, fmaxf(c1, n1));
            float vm2 = fmaxf(pv2, fmaxf(c2, n2));
            float vm3 = fmaxf(pv3, fmaxf(c3, n3));
            float lL = __shfl_up(vm3, 1);
            lL = (lane == 0) ? SENT : lL;
            float rR = __shfl_down(vm0, 1);
            rR = (lane == 63) ? SENT : rR;
            float h0 = fmaxf(lL,  fmaxf(vm0, vm1));
            float h1 = fmaxf(vm0, fmaxf(vm1, vm2));
            float h2 = fmaxf(vm1, fmaxf(vm2, vm3));
            float h3 = fmaxf(vm2, fmaxf(vm3, rR));
            v[i][0] = fmaxf(c0, fmaf(p[i][0], h0 - r[i][0], r[i][0]));
            v[i][1] = fmaxf(c1, fmaf(p[i][1], h1 - r[i][1], r[i][1]));
            v[i][2] = fmaxf(c2, fmaf(p[i][2], h2 - r[i][2], r[i][2]));
            v[i][3] = fmaxf(c3, fmaf(p[i][3], h3 - r[i][3], r[i][3]));
            pv0 = c0; pv1 = c1; pv2 = c2; pv3 = c3;
        }
    }

    const float* occ = image + (size_t)b * 131072;
#pragma unroll
    for (int i = 0; i < 7; ++i) {
        int e = w * 7 + i;
        if (e >= 20 && e < 36) {
            int gy = gy0 + e;
            float4 ov = *(const float4*)&occ[gy * 256 + x4];
            float4 o;
            o.x = (ov.x > 0.49f) ? v[i][0] : -1.f;
            o.y = (ov.y > 0.49f) ? v[i][1] : -1.f;
            o.z = (ov.z > 0.49f) ? v[i][2] : -1.f;
            o.w = (ov.w > 0.49f) ? v[i][3] : -1.f;
            *(float4*)&out[(size_t)b * 65536 + gy * 256 + x4] = o;
        }
    }
}

extern "C" void kernel_launch(void* const* d_in, const int* in_sizes, int n_in,
                              void* d_out, int out_size, void* d_ws, size_t ws_size,
                              hipStream_t stream) {
    const float* image = (const float*)d_in[0];  // (16,2,256,256)
    const float* Wh    = (const float*)d_in[1];  // (150,1,3,3)
    const float* bh    = (const float*)d_in[2];  // (150,)
    const float* Wp    = (const float*)d_in[3];  // (1,150,1,1)
    float* out  = (float*)d_out;                 // (16,1,256,256) f32
    float* pbuf = (float*)d_ws;                  // 4 MB scratch for p
    uint4* wsA  = (uint4*)((char*)d_ws + (4 << 20));  // A-fragments + header

    pack_a_kernel<<<1, 256, 0, stream>>>(Wh, bh, Wp, wsA);
    conv_p_mfma<<<dim3(8, 64, 16), dim3(256), 0, stream>>>(image, wsA, pbuf);
    mvprop_kernel<<<dim3(1, 16, 16), dim3(512), 0, stream>>>(image, pbuf, out);
}